// Round 9
// baseline (361.504 us; speedup 1.0000x reference)
//
#include <hip/hip_runtime.h>
#include <hip/hip_bf16.h>

__device__ __forceinline__ float bf2f(unsigned short u) {
    union { unsigned int i; float f; } v; v.i = ((unsigned int)u) << 16; return v.f;
}
__device__ __forceinline__ unsigned short f2bf(float f) {
    __hip_bfloat16 h = __float2bfloat16(f);
    return *reinterpret_cast<unsigned short*>(&h);
}
// XOR swizzle for uint4 slots within a 128-slot (2 KB) region: spreads the
// 32B-stride pixel pattern across all LDS bank groups.
__device__ __forceinline__ int swz(int idx) { return idx ^ ((idx >> 3) & 7); }

__device__ __forceinline__ float dot8(const float* q, uint4 k) {
    const unsigned short* u = (const unsigned short*)&k;
    float s = 0.f;
    #pragma unroll
    for (int c = 0; c < 8; ++c) s += q[c] * bf2f(u[c]);
    return s;
}
__device__ __forceinline__ void axpy8(float* acc, float pw, uint4 v) {
    const unsigned short* u = (const unsigned short*)&v;
    #pragma unroll
    for (int c = 0; c < 8; ++c) acc[c] += pw * bf2f(u[c]);
}

// ws: Q fp32 [b][g][pix][ci] (4 MB) | K bf16 (2 MB) | V bf16 (2 MB)

// ---------------------------------------------------------------------------
// conv: three 1x1 convs, fp32 in/weights, fp32 accum. (unchanged from R8)
// 32-px tiles -> grid (256,3). thread = 8 ch x 2 px.
// ---------------------------------------------------------------------------
__global__ __launch_bounds__(256) void conv_kernel(
    const float* __restrict__ fm,
    const float* __restrict__ wq, const float* __restrict__ wk,
    const float* __restrict__ wv,
    float* __restrict__ Qout,
    unsigned short* __restrict__ K0,
    unsigned short* __restrict__ V0)
{
    const int sel = blockIdx.y;
    const float* W = (sel == 0) ? wq : ((sel == 1) ? wk : wv);
    const int c0 = (sel == 0) ? 128 : 0;

    __shared__ float w_s[64 * 132];
    __shared__ float x_s[64 * 36];

    const int tid = threadIdx.x;
    const int P0  = blockIdx.x * 32;
    const int b   = P0 >> 12;
    const int hw0 = P0 & 4095;

    float acc[8][2];
    #pragma unroll
    for (int i = 0; i < 8; ++i) { acc[i][0] = 0.f; acc[i][1] = 0.f; }

    const int ocb = (tid >> 4) * 8;
    const int pxb = (tid & 15) * 2;

    for (int kh = 0; kh < 128; kh += 64) {
        {
            const int o    = tid >> 1;
            const int koff = (tid & 1) * 32;
            #pragma unroll
            for (int i = 0; i < 8; ++i) {
                float4 v = *(const float4*)(W + o * 128 + kh + koff + i * 4);
                w_s[(koff + i * 4 + 0) * 132 + o] = v.x;
                w_s[(koff + i * 4 + 1) * 132 + o] = v.y;
                w_s[(koff + i * 4 + 2) * 132 + o] = v.z;
                w_s[(koff + i * 4 + 3) * 132 + o] = v.w;
            }
        }
        {
            const int c  = tid >> 2;
            const int pc = (tid & 3) * 8;
            const float* src = fm + (((size_t)(b * 256 + c0 + kh + c)) << 12) + hw0 + pc;
            *(float4*)(&x_s[c * 36 + pc])     = *(const float4*)src;
            *(float4*)(&x_s[c * 36 + pc + 4]) = *(const float4*)(src + 4);
        }
        __syncthreads();
        #pragma unroll 8
        for (int k = 0; k < 64; ++k) {
            const float* kw = &w_s[k * 132 + ocb];
            float4 wa = *(const float4*)kw;
            float4 wb = *(const float4*)(kw + 4);
            float2 xv = *(const float2*)(&x_s[k * 36 + pxb]);
            const float wf[8] = {wa.x, wa.y, wa.z, wa.w, wb.x, wb.y, wb.z, wb.w};
            #pragma unroll
            for (int i = 0; i < 8; ++i) {
                acc[i][0] += wf[i] * xv.x;
                acc[i][1] += wf[i] * xv.y;
            }
        }
        __syncthreads();
    }

    const int g   = ocb >> 4;
    const int lci = ocb & 8;
    #pragma unroll
    for (int pj = 0; pj < 2; ++pj) {
        const int hw = hw0 + pxb + pj;
        const size_t base = ((((size_t)(b * 8 + g)) << 12) + hw) * 16 + lci;
        if (sel == 0) {
            *(float4*)(Qout + base)     = make_float4(acc[0][pj], acc[1][pj], acc[2][pj], acc[3][pj]);
            *(float4*)(Qout + base + 4) = make_float4(acc[4][pj], acc[5][pj], acc[6][pj], acc[7][pj]);
        } else {
            unsigned short tmp[8];
            #pragma unroll
            for (int i = 0; i < 8; ++i) tmp[i] = f2bf(acc[i][pj]);
            unsigned short* dst = ((sel == 1) ? K0 : V0) + base;
            *(uint4*)dst = *(const uint4*)tmp;
        }
    }
}

// ---------------------------------------------------------------------------
// attn A: main 7x7 (rel bias) + row refine. LDS 10-row K/V band, XOR-swizzled
// uint4 slots. block 256 = 4 rows x 64 px; grid (16, 8, 2). VGPR cap 128.
// ---------------------------------------------------------------------------
__global__ __launch_bounds__(256, 4) void attnA_kernel(
    const float* __restrict__ Q,
    const unsigned short* __restrict__ K0,
    const unsigned short* __restrict__ V0,
    const float* __restrict__ rel_h,
    const float* __restrict__ rel_w,
    float* __restrict__ out)
{
    __shared__ uint4 ks4[10 * 128];   // 20 KB, swizzled slots per 128-slot row
    __shared__ uint4 vs4[10 * 128];   // 20 KB

    const int tid = threadIdx.x;
    const int ty  = tid >> 6;          // 0..3
    const int w   = tid & 63;
    const int h0  = blockIdx.x * 4;
    const int h   = h0 + ty;
    const int g   = blockIdx.y;
    const int b   = blockIdx.z;
    const size_t slab = ((size_t)(b * 8 + g)) << 16;

    // stage rows h0-3 .. h0+6 of K and V (OOB rows -> zeros)
    {
        const uint4* Ksrc = (const uint4*)(K0 + slab);
        const uint4* Vsrc = (const uint4*)(V0 + slab);
        #pragma unroll
        for (int it = 0; it < 5; ++it) {
            const int idx = tid + it * 256;   // 0..1279
            const int row = idx >> 7;         // 0..9
            const int off = idx & 127;        // uint4 within row
            const int rg  = h0 - 3 + row;
            uint4 kz = make_uint4(0u,0u,0u,0u), vz = make_uint4(0u,0u,0u,0u);
            if (rg >= 0 && rg < 64) {
                kz = Ksrc[rg * 128 + off];
                vz = Vsrc[rg * 128 + off];
            }
            const int l = row * 128 + swz(off);
            ks4[l] = kz;
            vs4[l] = vz;
        }
    }
    __syncthreads();

    float qr[16];
    {
        const float* qp = Q + slab + (size_t)(h * 64 + w) * 16;
        #pragma unroll
        for (int ci = 0; ci < 16; ++ci) qr[ci] = qp[ci];
    }

    float qrel[7];
    {
        const float* rel = (g < 4) ? (rel_h + g * 112) : (rel_w + (g - 4) * 112);
        #pragma unroll
        for (int t = 0; t < 7; ++t) {
            float s = 0.f;
            #pragma unroll
            for (int ci = 0; ci < 16; ++ci) s += qr[ci] * rel[ci * 7 + t];
            qrel[t] = s;
        }
    }

    float acc[16];
    #pragma unroll
    for (int ci = 0; ci < 16; ++ci) acc[ci] = 0.f;

    float sc[49];
    // ---- main 7x7 scores (LDS rows ty..ty+6) ----
    {
        float mx = -3.4e38f;
        #pragma unroll
        for (int i = 0; i < 7; ++i) {
            const uint4* krow = ks4 + (ty + i) * 128;
            #pragma unroll
            for (int j = 0; j < 7; ++j) {
                const int x = w + j - 3;
                const bool xin = (unsigned)x < 64u;
                const int xc = xin ? x : 0;
                uint4 k0 = krow[swz(xc * 2)];
                uint4 k1 = krow[swz(xc * 2 + 1)];
                float d = dot8(qr, k0) + dot8(qr + 8, k1);
                d = xin ? d : 0.f;
                d += qrel[(g < 4) ? i : j];
                sc[i * 7 + j] = d;
                mx = fmaxf(mx, d);
            }
        }
        float den = 0.f;
        #pragma unroll
        for (int k = 0; k < 49; ++k) { sc[k] = __expf(sc[k] - mx); den += sc[k]; }
        const float inv = 1.f / den;
        #pragma unroll
        for (int i = 0; i < 7; ++i) {
            const uint4* vrow = vs4 + (ty + i) * 128;
            #pragma unroll
            for (int j = 0; j < 7; ++j) {
                const int x = w + j - 3;
                const bool xin = (unsigned)x < 64u;
                const int xc = xin ? x : 0;
                const float pw = xin ? sc[i * 7 + j] * inv : 0.f;
                uint4 v0 = vrow[swz(xc * 2)];
                uint4 v1 = vrow[swz(xc * 2 + 1)];
                axpy8(acc, pw, v0);
                axpy8(acc + 8, pw, v1);
            }
        }
    }
    // ---- row refine (LDS row ty+3) ----
    {
        const uint4* krow = ks4 + (ty + 3) * 128;
        const uint4* vrow = vs4 + (ty + 3) * 128;
        float sr[15];
        float mx = -3.4e38f;
        #pragma unroll
        for (int j = 0; j < 15; ++j) {
            const int x = w + j - 7;
            const bool xin = (unsigned)x < 64u;
            const int xc = xin ? x : 0;
            uint4 k0 = krow[swz(xc * 2)];
            uint4 k1 = krow[swz(xc * 2 + 1)];
            float d = dot8(qr, k0) + dot8(qr + 8, k1);
            d = xin ? d : 0.f;
            sr[j] = d;
            mx = fmaxf(mx, d);
        }
        float den = 0.f;
        #pragma unroll
        for (int j = 0; j < 15; ++j) { sr[j] = __expf(sr[j] - mx); den += sr[j]; }
        const float inv = 1.f / den;
        #pragma unroll
        for (int j = 0; j < 15; ++j) {
            const int x = w + j - 7;
            const bool xin = (unsigned)x < 64u;
            const int xc = xin ? x : 0;
            const float pw = xin ? sr[j] * inv : 0.f;
            uint4 v0 = vrow[swz(xc * 2)];
            uint4 v1 = vrow[swz(xc * 2 + 1)];
            axpy8(acc, pw, v0);
            axpy8(acc + 8, pw, v1);
        }
    }

    float* op = out + (((size_t)(b * 128 + g * 16)) << 12) + h * 64 + w;
    #pragma unroll
    for (int ci = 0; ci < 16; ++ci) op[(size_t)ci << 12] = acc[ci];
}

// ---------------------------------------------------------------------------
// attn B: col refine. LDS 4-column K/V band, swizzled. block 256 = 4 cols x
// 64 h; grid (16, 8, 2). out += (after A in stream order).
// ---------------------------------------------------------------------------
__global__ __launch_bounds__(256, 4) void attnB_kernel(
    const float* __restrict__ Q,
    const unsigned short* __restrict__ K0,
    const unsigned short* __restrict__ V0,
    float* __restrict__ out)
{
    __shared__ uint4 ks4[4 * 128];   // 8 KB: [w'][swizzled 128 slots]
    __shared__ uint4 vs4[4 * 128];   // 8 KB

    const int tid = threadIdx.x;
    const int wl  = tid >> 6;          // 0..3
    const int h   = tid & 63;
    const int w0  = blockIdx.x * 4;
    const int g   = blockIdx.y;
    const int b   = blockIdx.z;
    const size_t slab = ((size_t)(b * 8 + g)) << 16;

    {
        const uint4* Ksrc = (const uint4*)(K0 + slab);
        const uint4* Vsrc = (const uint4*)(V0 + slab);
        #pragma unroll
        for (int it = 0; it < 2; ++it) {
            const int idx  = tid + it * 256;   // 0..511
            const int hh   = idx >> 3;         // 0..63
            const int rem  = idx & 7;
            const int wp   = rem >> 1;         // 0..3
            const int half = rem & 1;
            const int gidx = (hh * 64 + w0 + wp) * 2 + half;
            const int lidx = wp * 128 + swz(hh * 2 + half);
            ks4[lidx] = Ksrc[gidx];
            vs4[lidx] = Vsrc[gidx];
        }
    }
    __syncthreads();

    float qr[16];
    {
        const float* qp = Q + slab + (size_t)(h * 64 + w0 + wl) * 16;
        #pragma unroll
        for (int ci = 0; ci < 16; ++ci) qr[ci] = qp[ci];
    }

    const uint4* kcol = ks4 + wl * 128;
    const uint4* vcol = vs4 + wl * 128;

    float sc[15];
    float mx = -3.4e38f;
    #pragma unroll
    for (int i = 0; i < 15; ++i) {
        const int y = h + i - 7;
        const bool yin = (unsigned)y < 64u;
        const int yc = yin ? y : 0;
        uint4 k0 = kcol[swz(yc * 2)];
        uint4 k1 = kcol[swz(yc * 2 + 1)];
        float d = dot8(qr, k0) + dot8(qr + 8, k1);
        d = yin ? d : 0.f;
        sc[i] = d;
        mx = fmaxf(mx, d);
    }
    float den = 0.f;
    #pragma unroll
    for (int i = 0; i < 15; ++i) { sc[i] = __expf(sc[i] - mx); den += sc[i]; }
    const float inv = 1.f / den;

    float acc[16];
    #pragma unroll
    for (int ci = 0; ci < 16; ++ci) acc[ci] = 0.f;
    #pragma unroll
    for (int i = 0; i < 15; ++i) {
        const int y = h + i - 7;
        const bool yin = (unsigned)y < 64u;
        const int yc = yin ? y : 0;
        const float pw = yin ? sc[i] * inv : 0.f;
        uint4 v0 = vcol[swz(yc * 2)];
        uint4 v1 = vcol[swz(yc * 2 + 1)];
        axpy8(acc, pw, v0);
        axpy8(acc + 8, pw, v1);
    }

    float* op = out + (((size_t)(b * 128 + g * 16)) << 12) + h * 64 + (w0 + wl);
    #pragma unroll
    for (int ci = 0; ci < 16; ++ci) {
        float* p = op + ((size_t)ci << 12);
        *p = *p + acc[ci];
    }
}

// ---------------------------------------------------------------------------
extern "C" void kernel_launch(void* const* d_in, const int* in_sizes, int n_in,
                              void* d_out, int out_size, void* d_ws, size_t ws_size,
                              hipStream_t stream) {
    (void)in_sizes; (void)n_in; (void)out_size; (void)ws_size;
    const float* fm    = (const float*)d_in[0];
    const float* wq    = (const float*)d_in[1];
    const float* wk    = (const float*)d_in[2];
    const float* wv    = (const float*)d_in[3];
    const float* rel_h = (const float*)d_in[4];
    const float* rel_w = (const float*)d_in[5];

    float* Q = (float*)d_ws;                               // 1048576 floats
    unsigned short* K0 = (unsigned short*)(Q + 1048576);   // 1048576 shorts
    unsigned short* V0 = K0 + 1048576;                     // 1048576 shorts

    conv_kernel<<<dim3(256, 3, 1), dim3(256), 0, stream>>>(
        fm, wq, wk, wv, Q, K0, V0);
    attnA_kernel<<<dim3(16, 8, 2), dim3(256), 0, stream>>>(
        Q, K0, V0, rel_h, rel_w, (float*)d_out);
    attnB_kernel<<<dim3(16, 8, 2), dim3(256), 0, stream>>>(
        Q, K0, V0, (float*)d_out);
}

// Round 10
// 124.586 us; speedup vs baseline: 2.9016x; 2.9016x over previous
//
#include <hip/hip_runtime.h>
#include <hip/hip_bf16.h>

__device__ __forceinline__ float bf2f(unsigned short u) {
    union { unsigned int i; float f; } v; v.i = ((unsigned int)u) << 16; return v.f;
}
__device__ __forceinline__ unsigned short f2bf(float f) {
    __hip_bfloat16 h = __float2bfloat16(f);
    return *reinterpret_cast<unsigned short*>(&h);
}
// XOR swizzle for uint4 slots within a 128-slot (2 KB) region.
__device__ __forceinline__ int swz(int idx) { return idx ^ ((idx >> 3) & 7); }

__device__ __forceinline__ float dot8(const float* q, uint4 k) {
    const unsigned short* u = (const unsigned short*)&k;
    float s = 0.f;
    #pragma unroll
    for (int c = 0; c < 8; ++c) s += q[c] * bf2f(u[c]);
    return s;
}
__device__ __forceinline__ void axpy8(float* acc, float pw, uint4 v) {
    const unsigned short* u = (const unsigned short*)&v;
    #pragma unroll
    for (int c = 0; c < 8; ++c) acc[c] += pw * bf2f(u[c]);
}

// ws: Q fp32 [b][g][pix][ci] (4 MB) | K bf16 (2 MB) | V bf16 (2 MB)

// ---------------------------------------------------------------------------
// conv: three 1x1 convs, fp32 in/weights, fp32 accum. (unchanged from R8)
// ---------------------------------------------------------------------------
__global__ __launch_bounds__(256) void conv_kernel(
    const float* __restrict__ fm,
    const float* __restrict__ wq, const float* __restrict__ wk,
    const float* __restrict__ wv,
    float* __restrict__ Qout,
    unsigned short* __restrict__ K0,
    unsigned short* __restrict__ V0)
{
    const int sel = blockIdx.y;
    const float* W = (sel == 0) ? wq : ((sel == 1) ? wk : wv);
    const int c0 = (sel == 0) ? 128 : 0;

    __shared__ float w_s[64 * 132];
    __shared__ float x_s[64 * 36];

    const int tid = threadIdx.x;
    const int P0  = blockIdx.x * 32;
    const int b   = P0 >> 12;
    const int hw0 = P0 & 4095;

    float acc[8][2];
    #pragma unroll
    for (int i = 0; i < 8; ++i) { acc[i][0] = 0.f; acc[i][1] = 0.f; }

    const int ocb = (tid >> 4) * 8;
    const int pxb = (tid & 15) * 2;

    for (int kh = 0; kh < 128; kh += 64) {
        {
            const int o    = tid >> 1;
            const int koff = (tid & 1) * 32;
            #pragma unroll
            for (int i = 0; i < 8; ++i) {
                float4 v = *(const float4*)(W + o * 128 + kh + koff + i * 4);
                w_s[(koff + i * 4 + 0) * 132 + o] = v.x;
                w_s[(koff + i * 4 + 1) * 132 + o] = v.y;
                w_s[(koff + i * 4 + 2) * 132 + o] = v.z;
                w_s[(koff + i * 4 + 3) * 132 + o] = v.w;
            }
        }
        {
            const int c  = tid >> 2;
            const int pc = (tid & 3) * 8;
            const float* src = fm + (((size_t)(b * 256 + c0 + kh + c)) << 12) + hw0 + pc;
            *(float4*)(&x_s[c * 36 + pc])     = *(const float4*)src;
            *(float4*)(&x_s[c * 36 + pc + 4]) = *(const float4*)(src + 4);
        }
        __syncthreads();
        #pragma unroll 8
        for (int k = 0; k < 64; ++k) {
            const float* kw = &w_s[k * 132 + ocb];
            float4 wa = *(const float4*)kw;
            float4 wb = *(const float4*)(kw + 4);
            float2 xv = *(const float2*)(&x_s[k * 36 + pxb]);
            const float wf[8] = {wa.x, wa.y, wa.z, wa.w, wb.x, wb.y, wb.z, wb.w};
            #pragma unroll
            for (int i = 0; i < 8; ++i) {
                acc[i][0] += wf[i] * xv.x;
                acc[i][1] += wf[i] * xv.y;
            }
        }
        __syncthreads();
    }

    const int g   = ocb >> 4;
    const int lci = ocb & 8;
    #pragma unroll
    for (int pj = 0; pj < 2; ++pj) {
        const int hw = hw0 + pxb + pj;
        const size_t base = ((((size_t)(b * 8 + g)) << 12) + hw) * 16 + lci;
        if (sel == 0) {
            *(float4*)(Qout + base)     = make_float4(acc[0][pj], acc[1][pj], acc[2][pj], acc[3][pj]);
            *(float4*)(Qout + base + 4) = make_float4(acc[4][pj], acc[5][pj], acc[6][pj], acc[7][pj]);
        } else {
            unsigned short tmp[8];
            #pragma unroll
            for (int i = 0; i < 8; ++i) tmp[i] = f2bf(acc[i][pj]);
            unsigned short* dst = ((sel == 1) ? K0 : V0) + base;
            *(uint4*)dst = *(const uint4*)tmp;
        }
    }
}

// ---------------------------------------------------------------------------
// attn A: main 7x7 (rel bias) + row refine. LDS 10-row K/V band (swizzled).
// Register-lean order: all scores -> softmaxes -> V in two 8-channel passes.
// block 256 = 4 rows x 64 px; grid (16, 8, 2). No occupancy arg (R9 lesson).
// ---------------------------------------------------------------------------
__global__ __launch_bounds__(256) void attnA_kernel(
    const float* __restrict__ Q,
    const unsigned short* __restrict__ K0,
    const unsigned short* __restrict__ V0,
    const float* __restrict__ rel_h,
    const float* __restrict__ rel_w,
    float* __restrict__ out)
{
    __shared__ uint4 ks4[10 * 128];   // 20 KB
    __shared__ uint4 vs4[10 * 128];   // 20 KB

    const int tid = threadIdx.x;
    const int ty  = tid >> 6;
    const int w   = tid & 63;
    const int h0  = blockIdx.x * 4;
    const int h   = h0 + ty;
    const int g   = blockIdx.y;
    const int b   = blockIdx.z;
    const size_t slab = ((size_t)(b * 8 + g)) << 16;

    {
        const uint4* Ksrc = (const uint4*)(K0 + slab);
        const uint4* Vsrc = (const uint4*)(V0 + slab);
        #pragma unroll
        for (int it = 0; it < 5; ++it) {
            const int idx = tid + it * 256;
            const int row = idx >> 7;
            const int off = idx & 127;
            const int rg  = h0 - 3 + row;
            uint4 kz = make_uint4(0u,0u,0u,0u), vz = make_uint4(0u,0u,0u,0u);
            if (rg >= 0 && rg < 64) {
                kz = Ksrc[rg * 128 + off];
                vz = Vsrc[rg * 128 + off];
            }
            const int l = row * 128 + swz(off);
            ks4[l] = kz;
            vs4[l] = vz;
        }
    }
    __syncthreads();

    float sc[49];
    float sr[15];
    {
        float qr[16];
        {
            const float* qp = Q + slab + (size_t)(h * 64 + w) * 16;
            #pragma unroll
            for (int ci = 0; ci < 16; ++ci) qr[ci] = qp[ci];
        }
        float qrel[7];
        {
            const float* rel = (g < 4) ? (rel_h + g * 112) : (rel_w + (g - 4) * 112);
            #pragma unroll
            for (int t = 0; t < 7; ++t) {
                float s = 0.f;
                #pragma unroll
                for (int ci = 0; ci < 16; ++ci) s += qr[ci] * rel[ci * 7 + t];
                qrel[t] = s;
            }
        }
        // main 7x7 scores
        float mx = -3.4e38f;
        #pragma unroll 1
        for (int i = 0; i < 7; ++i) {
            const uint4* krow = ks4 + (ty + i) * 128;
            #pragma unroll
            for (int j = 0; j < 7; ++j) {
                const int x = w + j - 3;
                const bool xin = (unsigned)x < 64u;
                const int xc = xin ? x : 0;
                uint4 k0 = krow[swz(xc * 2)];
                uint4 k1 = krow[swz(xc * 2 + 1)];
                float d = dot8(qr, k0) + dot8(qr + 8, k1);
                d = xin ? d : 0.f;
                d += qrel[(g < 4) ? i : j];
                sc[i * 7 + j] = d;
                mx = fmaxf(mx, d);
            }
        }
        float den = 0.f;
        #pragma unroll
        for (int k = 0; k < 49; ++k) { sc[k] = __expf(sc[k] - mx); den += sc[k]; }
        const float inv = 1.f / den;
        #pragma unroll
        for (int k = 0; k < 49; ++k) sc[k] *= inv;

        // row-refine scores (row ty+3)
        const uint4* krow = ks4 + (ty + 3) * 128;
        float mr = -3.4e38f;
        #pragma unroll 1
        for (int j = 0; j < 15; ++j) {
            const int x = w + j - 7;
            const bool xin = (unsigned)x < 64u;
            const int xc = xin ? x : 0;
            uint4 k0 = krow[swz(xc * 2)];
            uint4 k1 = krow[swz(xc * 2 + 1)];
            float d = dot8(qr, k0) + dot8(qr + 8, k1);
            d = xin ? d : 0.f;
            sr[j] = d;
            mr = fmaxf(mr, d);
        }
        float denr = 0.f;
        #pragma unroll
        for (int j = 0; j < 15; ++j) { sr[j] = __expf(sr[j] - mr); denr += sr[j]; }
        const float invr = 1.f / denr;
        #pragma unroll
        for (int j = 0; j < 15; ++j) sr[j] *= invr;
    }   // qr, qrel dead here

    // V accumulation in two 8-channel passes (acc = 8 regs live)
    float* op = out + (((size_t)(b * 128 + g * 16)) << 12) + h * 64 + w;
    #pragma unroll 1
    for (int half = 0; half < 2; ++half) {
        float acc[8];
        #pragma unroll
        for (int c = 0; c < 8; ++c) acc[c] = 0.f;
        #pragma unroll 1
        for (int i = 0; i < 7; ++i) {
            const uint4* vrow = vs4 + (ty + i) * 128;
            #pragma unroll
            for (int j = 0; j < 7; ++j) {
                const int x = w + j - 3;
                const bool xin = (unsigned)x < 64u;
                const int xc = xin ? x : 0;
                const float pw = xin ? sc[i * 7 + j] : 0.f;
                axpy8(acc, pw, vrow[swz(xc * 2 + half)]);
            }
        }
        {
            const uint4* vrow = vs4 + (ty + 3) * 128;
            #pragma unroll
            for (int j = 0; j < 15; ++j) {
                const int x = w + j - 7;
                const bool xin = (unsigned)x < 64u;
                const int xc = xin ? x : 0;
                const float pw = xin ? sr[j] : 0.f;
                axpy8(acc, pw, vrow[swz(xc * 2 + half)]);
            }
        }
        #pragma unroll
        for (int c = 0; c < 8; ++c)
            op[(size_t)(half * 8 + c) << 12] = acc[c];
    }
}

// ---------------------------------------------------------------------------
// attn B: col refine. LDS 4-column K/V band (swizzled). Scores then two
// 8-channel V passes. block 256 = 4 cols x 64 h; grid (16, 8, 2). out +=.
// ---------------------------------------------------------------------------
__global__ __launch_bounds__(256) void attnB_kernel(
    const float* __restrict__ Q,
    const unsigned short* __restrict__ K0,
    const unsigned short* __restrict__ V0,
    float* __restrict__ out)
{
    __shared__ uint4 ks4[4 * 128];   // 8 KB
    __shared__ uint4 vs4[4 * 128];   // 8 KB

    const int tid = threadIdx.x;
    const int wl  = tid >> 6;
    const int h   = tid & 63;
    const int w0  = blockIdx.x * 4;
    const int g   = blockIdx.y;
    const int b   = blockIdx.z;
    const size_t slab = ((size_t)(b * 8 + g)) << 16;

    {
        const uint4* Ksrc = (const uint4*)(K0 + slab);
        const uint4* Vsrc = (const uint4*)(V0 + slab);
        #pragma unroll
        for (int it = 0; it < 2; ++it) {
            const int idx  = tid + it * 256;
            const int hh   = idx >> 3;
            const int rem  = idx & 7;
            const int wp   = rem >> 1;
            const int half = rem & 1;
            const int gidx = (hh * 64 + w0 + wp) * 2 + half;
            const int lidx = wp * 128 + swz(hh * 2 + half);
            ks4[lidx] = Ksrc[gidx];
            vs4[lidx] = Vsrc[gidx];
        }
    }
    __syncthreads();

    const uint4* kcol = ks4 + wl * 128;
    const uint4* vcol = vs4 + wl * 128;

    float sc[15];
    {
        float qr[16];
        const float* qp = Q + slab + (size_t)(h * 64 + w0 + wl) * 16;
        #pragma unroll
        for (int ci = 0; ci < 16; ++ci) qr[ci] = qp[ci];

        float mx = -3.4e38f;
        #pragma unroll 1
        for (int i = 0; i < 15; ++i) {
            const int y = h + i - 7;
            const bool yin = (unsigned)y < 64u;
            const int yc = yin ? y : 0;
            uint4 k0 = kcol[swz(yc * 2)];
            uint4 k1 = kcol[swz(yc * 2 + 1)];
            float d = dot8(qr, k0) + dot8(qr + 8, k1);
            d = yin ? d : 0.f;
            sc[i] = d;
            mx = fmaxf(mx, d);
        }
        float den = 0.f;
        #pragma unroll
        for (int i = 0; i < 15; ++i) { sc[i] = __expf(sc[i] - mx); den += sc[i]; }
        const float inv = 1.f / den;
        #pragma unroll
        for (int i = 0; i < 15; ++i) sc[i] *= inv;
    }

    float* op = out + (((size_t)(b * 128 + g * 16)) << 12) + h * 64 + (w0 + wl);
    #pragma unroll 1
    for (int half = 0; half < 2; ++half) {
        float acc[8];
        #pragma unroll
        for (int c = 0; c < 8; ++c) acc[c] = 0.f;
        #pragma unroll
        for (int i = 0; i < 15; ++i) {
            const int y = h + i - 7;
            const bool yin = (unsigned)y < 64u;
            const int yc = yin ? y : 0;
            const float pw = yin ? sc[i] : 0.f;
            axpy8(acc, pw, vcol[swz(yc * 2 + half)]);
        }
        #pragma unroll
        for (int c = 0; c < 8; ++c) {
            float* p = op + ((size_t)(half * 8 + c) << 12);
            *p = *p + acc[c];
        }
    }
}

// ---------------------------------------------------------------------------
extern "C" void kernel_launch(void* const* d_in, const int* in_sizes, int n_in,
                              void* d_out, int out_size, void* d_ws, size_t ws_size,
                              hipStream_t stream) {
    (void)in_sizes; (void)n_in; (void)out_size; (void)ws_size;
    const float* fm    = (const float*)d_in[0];
    const float* wq    = (const float*)d_in[1];
    const float* wk    = (const float*)d_in[2];
    const float* wv    = (const float*)d_in[3];
    const float* rel_h = (const float*)d_in[4];
    const float* rel_w = (const float*)d_in[5];

    float* Q = (float*)d_ws;                               // 1048576 floats
    unsigned short* K0 = (unsigned short*)(Q + 1048576);   // 1048576 shorts
    unsigned short* V0 = K0 + 1048576;                     // 1048576 shorts

    conv_kernel<<<dim3(256, 3, 1), dim3(256), 0, stream>>>(
        fm, wq, wk, wv, Q, K0, V0);
    attnA_kernel<<<dim3(16, 8, 2), dim3(256), 0, stream>>>(
        Q, K0, V0, rel_h, rel_w, (float*)d_out);
    attnB_kernel<<<dim3(16, 8, 2), dim3(256), 0, stream>>>(
        Q, K0, V0, (float*)d_out);
}